// Round 18
// baseline (399.925 us; speedup 1.0000x reference)
//
#include <hip/hip_runtime.h>
#include <stdint.h>

#define N_NODES 4096
#define F_DIM   64
#define LRELU_ALPHA 0.2f

typedef _Float16 f16;
typedef __attribute__((ext_vector_type(8))) _Float16 half8;  // MFMA f16 A/B frag (4 VGPRs)
typedef __attribute__((ext_vector_type(4))) float f32x4;     // MFMA C/D frag

// ---------------------------------------------------------------------------
// Kernel 0+1 FUSED, roles interleaved 1:16 (unchanged from R17 proven-pass).
// pack: bits[row*128 + (j>>5)] bit (j&31) = adj[row][j] > 0.
// prep: Wh=h@W; ei,ej; whB in MFMA B-fragment order:
//   whB[((b*128+jc)*4+fc)*512 + (q*16+m)*8 + x] = Wh[j=jc*32+q*8+x][f=fc*16+m]
//   blockmax[pid] = max ej over the prep block's 16 rows.
// ---------------------------------------------------------------------------
__global__ __launch_bounds__(256) void gat_pp(
    const float* __restrict__ h, const float* __restrict__ W,
    const float* __restrict__ a, const int* __restrict__ adj,
    float* __restrict__ ei, float* __restrict__ ej,
    f16* __restrict__ whB, float* __restrict__ blockmax,
    uint32_t* __restrict__ bits)
{
  __shared__ float sh_h[4][F_DIM];
  __shared__ f16 tile[F_DIM][16];   // [f][loc]
  __shared__ float wmax[4];
  const int t = threadIdx.x, w = t >> 6, lane = t & 63;
  const int bid = blockIdx.x;
  const int pid = bid / 17;

  if (bid % 17 != 0) {
    const int r = bid - 1 - pid;                  // pack row (0..16383)
    const int* row = adj + (size_t)r * N_NODES;
    const int jw0 = w * 1024;
    int v[16];
#pragma unroll
    for (int p = 0; p < 16; ++p)
      v[p] = row[jw0 + p * 64 + lane];
#pragma unroll
    for (int p = 0; p < 16; ++p) {
      const unsigned long long m = __ballot(v[p] > 0);
      if (lane == 0)
        *(uint64_t*)(bits + (size_t)r * 128 + ((jw0 + p * 64) >> 5)) = m;
    }
    return;
  }

  const int n0 = pid * 16;
  const int b  = n0 >> 12;
  const int nl0 = n0 & (N_NODES - 1);

  float wcol[F_DIM];
#pragma unroll
  for (int k = 0; k < F_DIM; ++k) wcol[k] = W[k * F_DIM + lane];
  const float a1 = a[lane], a2 = a[F_DIM + lane];

  float runmax = -3e38f;
  for (int r = 0; r < 4; ++r) {
    const int loc = w * 4 + r;
    const int n = n0 + loc;
    const float hv = h[(size_t)n * F_DIM + lane];
    sh_h[w][lane] = hv;
    float wh = 0.f;
#pragma unroll
    for (int k = 0; k < F_DIM; k += 4) {
      const float4 hb = *(const float4*)(&sh_h[w][k]);
      wh = fmaf(hb.x, wcol[k + 0], wh);
      wh = fmaf(hb.y, wcol[k + 1], wh);
      wh = fmaf(hb.z, wcol[k + 2], wh);
      wh = fmaf(hb.w, wcol[k + 3], wh);
    }
    float s1 = wh * a1, s2 = wh * a2;
#pragma unroll
    for (int off = 32; off; off >>= 1) {
      s1 += __shfl_xor(s1, off);
      s2 += __shfl_xor(s2, off);
    }
    if (lane == 0) { ei[n] = s1; ej[n] = s2; }
    runmax = fmaxf(runmax, s2);
    tile[lane][loc] = (f16)wh;
  }
  if (lane == 0) wmax[w] = runmax;
  __syncthreads();

  {
    const int jc = nl0 >> 5;
    const int q0 = (nl0 >> 3) & 3;
    const int fc = t >> 6;
    const int r6 = t & 63;
    const int qp = r6 >> 5;
    const int m  = (r6 >> 1) & 15;
    const int xh = (t & 1) * 4;
    const int loc = qp * 8 + xh;
    f16* dst = whB + (((size_t)(b * 128 + jc)) * 4 + fc) * 512
                   + ((q0 + qp) * 16 + m) * 8 + xh;
    *(uint2*)dst = *(const uint2*)(&tile[fc * 16 + m][loc]);
  }
  if (t == 0)
    blockmax[pid] =
        fmaxf(fmaxf(wmax[0], wmax[1]), fmaxf(wmax[2], wmax[3]));
}

// ---------------------------------------------------------------------------
// Kernel 2: attention, LDS-RESIDENT inner loop. block = (64 rows, j-quarter),
// 256 thr = 4 waves = 4 row-tiles, all sweeping the SAME 1024-j window.
// Staged once per block: bits (8 KB, kills the 16-row-scattered load),
// ej (4 KB). whB staged per 32-j chunk (4 KB) double-buffered: the inner
// loop issues ONE global load per thread per chunk (prefetch) — vs R17's 6
// per wave-iter. Everything else reads LDS. Theory: attn's ~90 us is
// per-vmem-instruction overhead (only contiguity ever moved it; traffic and
// occupancy did nothing) -> collapsing vmem instr count should collapse time.
// Partial num/den per (row-chunk, jq) written to global; gat_red merges.
// lbits padded to 33 dwords/row -> 16 distinct banks, conflict-free.
// A-frag: A[m=lane&15][k=quad*8+x]; B-frag: B[k=quad*8+x][n=m];
// C/D: row=quad*4+reg, col=lane&15 (HW-verified m89/m91).
// ---------------------------------------------------------------------------
__global__ __launch_bounds__(256, 4) void gat_attn(
    const uint32_t* __restrict__ bits, const float* __restrict__ ei,
    const float* __restrict__ ej, const f16* __restrict__ whB,
    const float* __restrict__ blockmax,
    float* __restrict__ pnum, float* __restrict__ pden)
{
  __shared__ __align__(16) f16 lwh[2][2048];      // 8 KB (double buffer)
  __shared__ __align__(16) float lej[1024];       // 4 KB
  __shared__ uint32_t lbits[64][33];              // 8.25 KB (padded)

  const int t = threadIdx.x, w = t >> 6, lane = t & 63;
  const int quad = lane >> 4, m = lane & 15;
  const int jq  = blockIdx.x & 3;
  const int rcg = blockIdx.x >> 2;            // 0..255 global row-chunk
  const int b   = rcg >> 6;
  const int growbase = rcg * 64;              // global row base (=b*4096+rc0)

  // per-batch max(ej)
  float maxej;
  {
    const float4 v = *(const float4*)(blockmax + b * 256 + lane * 4);
    maxej = fmaxf(fmaxf(v.x, v.y), fmaxf(v.z, v.w));
#pragma unroll
    for (int off = 32; off; off >>= 1)
      maxej = fmaxf(maxej, __shfl_xor(maxej, off));
  }

  // this lane's row (same for all quads): i = growbase + w*16 + m
  const int rowg = growbase + w * 16 + m;
  const float ei_s = ei[rowg];
  float bnd = ei_s + maxej;
  bnd = fmaxf(bnd, LRELU_ALPHA * bnd);
  const float c1 = ei_s - bnd;
  const float c2 = LRELU_ALPHA * ei_s - bnd;

  // ---- stage bits (64 rows x 32 dwords) and ej (1024 floats) ----
#pragma unroll
  for (int pass = 0; pass < 8; ++pass) {
    const int r = pass * 8 + (t >> 5);
    const int dwi = t & 31;
    lbits[r][dwi] = bits[(size_t)(growbase + r) * 128 + jq * 32 + dwi];
  }
  *(float4*)(&lej[t * 4]) =
      *(const float4*)(ej + b * N_NODES + jq * 1024 + t * 4);

  // ---- stage whB chunk 0 ----
  const f16* whq = whB + ((size_t)(b * 128 + jq * 32)) * 2048;   // chunk base
  *(half8*)(&lwh[0][t * 8]) = *(const half8*)(whq + t * 8);
  __syncthreads();

  f32x4 acc[4] = {{0.f,0.f,0.f,0.f},{0.f,0.f,0.f,0.f},
                  {0.f,0.f,0.f,0.f},{0.f,0.f,0.f,0.f}};
  float den = 0.f;

  for (int c = 0; c < 32; ++c) {
    // prefetch next chunk into registers (the ONLY global load in the loop)
    half8 pre;
    if (c + 1 < 32)
      pre = *(const half8*)(whq + (size_t)(c + 1) * 2048 + t * 8);

    // compute chunk c from LDS
    const int buf = c & 1;
    const float4 e0 = *(const float4*)(&lej[c * 32 + quad * 8]);
    const float4 e1 = *(const float4*)(&lej[c * 32 + quad * 8 + 4]);
    const float ejA[8] = {e0.x, e0.y, e0.z, e0.w, e1.x, e1.y, e1.z, e1.w};
    const uint32_t dw = lbits[w * 16 + m][c];

    half8 bf[4];
#pragma unroll
    for (int fc = 0; fc < 4; ++fc)
      bf[fc] = *(const half8*)(&lwh[buf][fc * 512 + lane * 8]);

    half8 pa;
#pragma unroll
    for (int x = 0; x < 8; ++x) {
      const float e = ejA[x];
      const float g = fmaxf(e + c1, fmaf(LRELU_ALPHA, e, c2));
      const float p = ((dw >> (quad * 8 + x)) & 1u) ? __expf(g) : 0.f;
      pa[x] = (f16)p;
      den += (float)pa[x];
    }

#pragma unroll
    for (int fc = 0; fc < 4; ++fc)
      acc[fc] = __builtin_amdgcn_mfma_f32_16x16x32_f16(pa, bf[fc], acc[fc], 0, 0, 0);

    __syncthreads();                 // all waves done reading lwh[buf^1]
    if (c + 1 < 32)
      *(half8*)(&lwh[buf ^ 1][t * 8]) = pre;
    __syncthreads();                 // staged chunk visible
  }

  // den: lanes sharing a row live 16 apart
  den += __shfl_xor(den, 16);
  den += __shfl_xor(den, 32);
  if (lane < 16)
    pden[(size_t)jq * 16384 + growbase + w * 16 + lane] = den;

  // partial num: C/D row = quad*4+rg, col = fc*16+m
#pragma unroll
  for (int fc = 0; fc < 4; ++fc)
#pragma unroll
    for (int rg = 0; rg < 4; ++rg)
      pnum[((size_t)jq * 16384 + growbase + w * 16 + quad * 4 + rg) * F_DIM
           + fc * 16 + m] = acc[fc][rg];
}

// ---------------------------------------------------------------------------
// Kernel 3: merge the 4 j-quarter partials, divide, ELU, store. grid 1024.
// ---------------------------------------------------------------------------
__global__ __launch_bounds__(256) void gat_red(
    const float* __restrict__ pnum, const float* __restrict__ pden,
    float* __restrict__ out)
{
  const int idx = blockIdx.x * 256 + threadIdx.x;
  const int base = idx * 4;
  const int row = base >> 6, col = base & 63;
  float4 n = {0.f, 0.f, 0.f, 0.f};
  float d = 0.f;
#pragma unroll
  for (int q = 0; q < 4; ++q) {
    const float4 v = *(const float4*)(pnum + ((size_t)q * 16384 + row) * F_DIM + col);
    n.x += v.x; n.y += v.y; n.z += v.z; n.w += v.w;
    d += pden[(size_t)q * 16384 + row];
  }
  const float inv = (d > 0.f) ? (1.f / d) : 0.f;
  float4 v;
  v.x = n.x * inv; v.y = n.y * inv; v.z = n.z * inv; v.w = n.w * inv;
  v.x = (v.x > 0.f) ? v.x : expm1f(v.x);
  v.y = (v.y > 0.f) ? v.y : expm1f(v.y);
  v.z = (v.z > 0.f) ? v.z : expm1f(v.z);
  v.w = (v.w > 0.f) ? v.w : expm1f(v.w);
  *(float4*)(out + base) = v;
}

extern "C" void kernel_launch(void* const* d_in, const int* in_sizes, int n_in,
                              void* d_out, int out_size, void* d_ws, size_t ws_size,
                              hipStream_t stream) {
  const float* h   = (const float*)d_in[0];
  const int*   adj = (const int*)d_in[1];
  const float* W   = (const float*)d_in[2];
  const float* a   = (const float*)d_in[3];
  float* out = (float*)d_out;

  char* ws = (char*)d_ws;
  // Workspace (~27.7 MB):
  // [0,        +64 KB)  ei
  // [65536,    +64 KB)  ej
  // [131072,   +4 KB)   blockmax
  // [135168,   +2 MB)   whB
  // [2232320,  +8 MB)   bits
  // [10620928, +16 MB)  pnum (4 quarters x 16384 rows x 64 f)
  // [27398144, +256 KB) pden (4 x 16384)
  float*    ei       = (float*)ws;
  float*    ej       = (float*)(ws + 65536);
  float*    blockmax = (float*)(ws + 131072);
  f16*      whB      = (f16*)(ws + 135168);
  uint32_t* bits     = (uint32_t*)(ws + 2232320);
  float*    pnum     = (float*)(ws + 10620928);
  float*    pden     = (float*)(ws + 27398144);

  hipLaunchKernelGGL(gat_pp, dim3(17408), dim3(256), 0, stream,
                     h, W, a, adj, ei, ej, whB, blockmax, bits);
  hipLaunchKernelGGL(gat_attn, dim3(1024), dim3(256), 0, stream,
                     bits, ei, ej, whB, blockmax, pnum, pden);
  hipLaunchKernelGGL(gat_red, dim3(1024), dim3(256), 0, stream,
                     pnum, pden, out);
}